// Round 17
// baseline (127.622 us; speedup 1.0000x reference)
//
#include <hip/hip_runtime.h>
#include <hip/hip_bf16.h>

// Problem: B=4, S=4096, D_MODEL=200, head=50 (padded to 64), out fp32.
// Pipeline: proj (MFMA, coalesced LDS staging, in-kernel weight transpose,
//           wot built by grid-z=3 slice) -> flash attn (MFMA, KV-split 8,
//           BARRIER-FREE: K/V read directly from L2, no LDS, 2 q-tiles/wave,
//           K=32 QK^T, fixed-exponent softmax, bf16 partials) -> fused
//           combine+outproj (MFMA).
// R15 lesson: __launch_bounds__(256,5) caused VGPR-48 spills -> 2x regression.
// R16->R17: K/V tiles (64KB each per (b,z)) are L2-resident and shared by 32
// blocks; LDS staging was pure overhead (guide m169). Direct reads are
// byte-identical to what staging delivered.

typedef short s4 __attribute__((ext_vector_type(4)));
typedef short s8 __attribute__((ext_vector_type(8)));
typedef float f4 __attribute__((ext_vector_type(4)));
typedef unsigned u2 __attribute__((ext_vector_type(2)));

#define SLEN 4096
#define NB 4
#define DMODEL 200
#define HREAL 50
#define HP 64
#define DMP 208
#define XPAD 212
// (1/sqrt(50)) * log2(e) folded into WQ so softmax uses exp2 (v_exp_f32)
#define QSCALE 0.20402789f
// Fixed softmax exponent offset (log2 units); softmax is shift-invariant.
#define MFIX 24.0f

__device__ __forceinline__ short f2bf(float f) {
  unsigned u = __builtin_bit_cast(unsigned, f);
  u += 0x7FFFu + ((u >> 16) & 1u);
  return (short)(u >> 16);
}

__device__ __forceinline__ float bf2f(short s) {
  unsigned u = ((unsigned)(unsigned short)s) << 16;
  return __builtin_bit_cast(float, u);
}

__device__ __forceinline__ float fexp2(float x) { return __builtin_amdgcn_exp2f(x); }

// ---------------- projections: X[16384,200] @ W -> bf16 [16384,64] -----------
// mode 0: q->Qp (scaled), 1: k->Kp, 2: v->VpT (transposed store [B][64][S]),
// mode 3 (blocks x<52): build wot (transpose+pad+sum WO head blocks).
__global__ __launch_bounds__(256) void proj_kernel(
    const float* __restrict__ q, const float* __restrict__ k, const float* __restrict__ v,
    const float* __restrict__ WQ, const float* __restrict__ WK, const float* __restrict__ WV,
    const float* __restrict__ WO, short* __restrict__ Qp, short* __restrict__ Kp,
    short* __restrict__ VpT, short* __restrict__ wot) {
  const int mode = blockIdx.z;
  const int tid = threadIdx.x;
  if (mode == 3) {  // wot: 13312 entries over 52 blocks
    int id = blockIdx.x * 256 + tid;
    if (blockIdx.x < 52 && id < DMP * HP) {
      int dm = id / HP, e = id % HP;
      float vv = 0.f;
      if (dm < DMODEL && e < HREAL) {
        vv = WO[(e)*DMODEL + dm] + WO[(HREAL + e) * DMODEL + dm] +
             WO[(2 * HREAL + e) * DMODEL + dm] + WO[(3 * HREAL + e) * DMODEL + dm];
      }
      wot[dm * HP + e] = f2bf(vv);
    }
    return;
  }
  __shared__ __align__(16) short Xl[64 * XPAD];
  __shared__ __align__(16) short Wl[64 * XPAD];
  const float* X = (mode == 0) ? q : (mode == 1 ? k : v);
  const float* Wsrc = (mode == 0) ? WQ : (mode == 1 ? WK : WV);
  const int sb64 = blockIdx.x * 64;

  {
    // ---- stage X: 3200 contiguous f4 chunks (rows of 50) ----
    const f4* src = (const f4*)(X + (size_t)sb64 * DMODEL);
#pragma unroll
    for (int i = 0; i < 13; ++i) {
      int idx = tid + i * 256;
      if (idx < 3200) {
        f4 a = src[idx];
        int row = idx / 50, c = idx - row * 50;
        s4 bv;
#pragma unroll
        for (int j = 0; j < 4; ++j) bv[j] = f2bf(a[j]);
        *(s4*)(Xl + row * XPAD + c * 4) = bv;
      }
    }
    s4 z = {0, 0, 0, 0};
    if (tid < 192) {  // zero X pad cols 200..211
      int row = tid / 3, c = 200 + (tid - (tid / 3) * 3) * 4;
      *(s4*)(Xl + row * XPAD + c) = z;
    }
    // ---- transpose W [200][50] fp32 -> Wl[e][d] bf16 (e<50, d<200) ----
#pragma unroll
    for (int i = 0; i < 40; ++i) {
      int flat = tid + i * 256;
      if (flat < DMODEL * HREAL) {
        float vv = Wsrc[flat];
        int d = flat / HREAL, e = flat - HREAL * d;
        if (mode == 0) vv *= QSCALE;
        Wl[e * XPAD + d] = f2bf(vv);
      }
    }
    // ---- W pad zero (disjoint from transpose writes) ----
#pragma unroll
    for (int i = 0; i < 3; ++i) {  // rows 50..63, all cols: 742 s4 chunks
      int idx = tid + i * 256;
      if (idx < 742) *(s4*)(Wl + 50 * XPAD + idx * 4) = z;
    }
    if (tid < 150) {  // rows 0..49, cols 200..211: 150 s4 chunks
      int row = tid / 3, c = 200 + (tid - (tid / 3) * 3) * 4;
      *(s4*)(Wl + row * XPAD + c) = z;
    }
  }
  __syncthreads();

  const int lane = tid & 63, wid = tid >> 6;
  const int l15 = lane & 15, g = lane >> 4;
  const int row16 = wid * 16 + l15;
  const int sbase = sb64 + wid * 16;
  f4 acc[4] = {};
#pragma unroll
  for (int c = 0; c < 13; ++c) {
    int d0 = 16 * c + 4 * g;
    s4 af = *(const s4*)(Xl + row16 * XPAD + d0);
#pragma unroll
    for (int n = 0; n < 4; ++n) {
      s4 bf = *(const s4*)(Wl + (16 * n + l15) * XPAD + d0);
      acc[n] = __builtin_amdgcn_mfma_f32_16x16x16bf16_1k(af, bf, acc[n], 0, 0, 0);
    }
  }
  if (mode < 2) {
    short* OUT = (mode == 0) ? Qp : Kp;
#pragma unroll
    for (int n = 0; n < 4; ++n)
#pragma unroll
      for (int r = 0; r < 4; ++r) {
        int rr = sbase + 4 * g + r;
        OUT[rr * HP + 16 * n + l15] = f2bf(acc[n][r]);
      }
  } else {
#pragma unroll
    for (int n = 0; n < 4; ++n)
#pragma unroll
      for (int r = 0; r < 4; ++r) {
        int rr = sbase + 4 * g + r;
        int bb = rr >> 12, s = rr & 4095;
        VpT[((bb * HP) + 16 * n + l15) * SLEN + s] = f2bf(acc[n][r]);
      }
  }
}

// ---------------- flash attention, swapped-operand QK^T, KV-split ------------
// BARRIER-FREE: no LDS. K fragments read directly (wave covers 16 rows x
// 128B contiguous = perfectly coalesced); V^T fragments read directly (32B
// granule per d-row). Tiles are L2-resident (64KB K + 64KB V per (b,z),
// shared by 32 x-blocks). Fragment values byte-identical to the staged path.
__global__ __launch_bounds__(256, 4) void attn_kernel(
    const short* __restrict__ Qp, const short* __restrict__ Kp,
    const short* __restrict__ VpT, float* __restrict__ Lp,
    short* __restrict__ Opb) {
  const int tid = threadIdx.x;
  const int lane = tid & 63, wid = tid >> 6;
  const int l15 = lane & 15, g = lane >> 4;
  const int b = blockIdx.y, z = blockIdx.z;
  const int nsplit = gridDim.z;
  const int qrowA = blockIdx.x * 128 + wid * 32 + l15;
  const int qrowB = qrowA + 16;

  // Q fragments for K=32 MFMA: lane group g holds d 8g..8g+7 (+32 for frag 1)
  s8 qfA[2], qfB[2];
  {
    const short* qpa = Qp + (size_t)(b * SLEN + qrowA) * HP + 8 * g;
    const short* qpb = Qp + (size_t)(b * SLEN + qrowB) * HP + 8 * g;
    qfA[0] = *(const s8*)(qpa);
    qfA[1] = *(const s8*)(qpa + 32);
    qfB[0] = *(const s8*)(qpb);
    qfB[1] = *(const s8*)(qpb + 32);
  }

  const int kv0 = z * (SLEN / nsplit);
  // K: row = b*S + kv0 + 16t + l15, elements 8g.. / 32+8g..
  const short* kbase = Kp + ((size_t)(b * SLEN + kv0 + l15)) * HP + 8 * g;
  // V^T: row d = 16n + l15, keys kv0 + 16t + 4g..+3
  const short* vbase = VpT + ((size_t)(b * HP + l15)) * SLEN + kv0 + 4 * g;

  f4 oA[4] = {}, oB[4] = {};
  float lsumA = 0.f, lsumB = 0.f;
  const int nt = SLEN / nsplit / 16;  // 16-key tiles
#pragma unroll 2
  for (int t = 0; t < nt; ++t) {
    // S^T tile [16 keys x 16 q] = K_tile . Q^T  (C: col=q=l15, row=key=4g+r)
    f4 stA, stB;
    {
      const short* kp = kbase + (size_t)t * 16 * HP;
      s8 kf0 = *(const s8*)(kp);
      s8 kf1 = *(const s8*)(kp + 32);
      __builtin_amdgcn_s_setprio(1);
      stA = __builtin_amdgcn_mfma_f32_16x16x32_bf16(kf0, qfA[0], (f4){}, 0, 0, 0);
      stB = __builtin_amdgcn_mfma_f32_16x16x32_bf16(kf0, qfB[0], (f4){}, 0, 0, 0);
      stA = __builtin_amdgcn_mfma_f32_16x16x32_bf16(kf1, qfA[1], stA, 0, 0, 0);
      stB = __builtin_amdgcn_mfma_f32_16x16x32_bf16(kf1, qfB[1], stB, 0, 0, 0);
      __builtin_amdgcn_s_setprio(0);
    }
    // ---- fixed-exponent softmax (branch-free) ----
    float pa0 = fexp2(stA[0] - MFIX), pa1 = fexp2(stA[1] - MFIX);
    float pa2 = fexp2(stA[2] - MFIX), pa3 = fexp2(stA[3] - MFIX);
    lsumA += (pa0 + pa1) + (pa2 + pa3);
    union { unsigned u[2]; s4 s; } puA;
    asm("v_cvt_pk_bf16_f32 %0, %1, %2" : "=v"(puA.u[0]) : "v"(pa0), "v"(pa1));
    asm("v_cvt_pk_bf16_f32 %0, %1, %2" : "=v"(puA.u[1]) : "v"(pa2), "v"(pa3));
    s4 pfA = puA.s;
    float pb0 = fexp2(stB[0] - MFIX), pb1 = fexp2(stB[1] - MFIX);
    float pb2 = fexp2(stB[2] - MFIX), pb3 = fexp2(stB[3] - MFIX);
    lsumB += (pb0 + pb1) + (pb2 + pb3);
    union { unsigned u[2]; s4 s; } puB;
    asm("v_cvt_pk_bf16_f32 %0, %1, %2" : "=v"(puB.u[0]) : "v"(pb0), "v"(pb1));
    asm("v_cvt_pk_bf16_f32 %0, %1, %2" : "=v"(puB.u[1]) : "v"(pb2), "v"(pb3));
    s4 pfB = puB.s;
    // O^T[d][q] += V^T . P  (P already in B-frag layout: col=q=l15, k=4g+r)
    const short* vp = vbase + 16 * t;
    __builtin_amdgcn_s_setprio(1);
#pragma unroll
    for (int n = 0; n < 4; ++n) {
      s4 vf = *(const s4*)(vp + (size_t)n * 16 * SLEN);
      oA[n] = __builtin_amdgcn_mfma_f32_16x16x16bf16_1k(vf, pfA, oA[n], 0, 0, 0);
      oB[n] = __builtin_amdgcn_mfma_f32_16x16x16bf16_1k(vf, pfB, oB[n], 0, 0, 0);
    }
    __builtin_amdgcn_s_setprio(0);
  }
  lsumA += __shfl_xor(lsumA, 16);
  lsumA += __shfl_xor(lsumA, 32);
  lsumB += __shfl_xor(lsumB, 16);
  lsumB += __shfl_xor(lsumB, 32);
  const int rowgA = b * SLEN + qrowA;
  const int rowgB = b * SLEN + qrowB;
  const int NR = NB * SLEN;
  if (lane < 16) {
    Lp[z * NR + rowgA] = lsumA;
    Lp[z * NR + rowgB] = lsumB;
  }
  // bf16 partial store (cvt_pk): halves split traffic
  short* opA = Opb + ((size_t)z * NR + rowgA) * HP;
  short* opB = Opb + ((size_t)z * NR + rowgB) * HP;
#pragma unroll
  for (int n = 0; n < 4; ++n) {
    u2 ua, ub;
    asm("v_cvt_pk_bf16_f32 %0, %1, %2" : "=v"(ua[0]) : "v"(oA[n][0]), "v"(oA[n][1]));
    asm("v_cvt_pk_bf16_f32 %0, %1, %2" : "=v"(ua[1]) : "v"(oA[n][2]), "v"(oA[n][3]));
    asm("v_cvt_pk_bf16_f32 %0, %1, %2" : "=v"(ub[0]) : "v"(oB[n][0]), "v"(oB[n][1]));
    asm("v_cvt_pk_bf16_f32 %0, %1, %2" : "=v"(ub[1]) : "v"(oB[n][2]), "v"(oB[n][3]));
    *(u2*)(opA + 16 * n + 4 * g) = ua;
    *(u2*)(opB + 16 * n + 4 * g) = ub;
  }
}

// ------- fused: merge KV-split partials (plain sums) + out-projection --------
template <int NSPLIT>
__global__ __launch_bounds__(256) void combineproj_kernel(
    const float* __restrict__ Lp, const short* __restrict__ Opb,
    const short* __restrict__ wot, float* __restrict__ out) {
  const int lane = threadIdx.x & 63, wid = threadIdx.x >> 6;
  const int l15 = lane & 15, g = lane >> 4;
  const int sbase = blockIdx.x * 64 + wid * 16;
  const int row = sbase + l15;
  const int NR = NB * SLEN;
  float L = 0.f;
#pragma unroll
  for (int s = 0; s < NSPLIT; ++s) L += Lp[s * NR + row];
  float inv = 1.0f / L;
  s4 af[4];
#pragma unroll
  for (int c = 0; c < 4; ++c) {
    f4 acc = {};
#pragma unroll
    for (int s = 0; s < NSPLIT; ++s) {
      s4 sv = *(const s4*)(Opb + ((size_t)s * NR + row) * HP + 16 * c + 4 * g);
      acc[0] += bf2f(sv[0]);
      acc[1] += bf2f(sv[1]);
      acc[2] += bf2f(sv[2]);
      acc[3] += bf2f(sv[3]);
    }
#pragma unroll
    for (int r = 0; r < 4; ++r) af[c][r] = f2bf(acc[r] * inv);
  }
  for (int n = 0; n < 13; ++n) {
    f4 acc = {};
    const short* brow = wot + (16 * n + l15) * HP + 4 * g;
#pragma unroll
    for (int c = 0; c < 4; ++c) {
      s4 bf = *(const s4*)(brow + 16 * c);
      acc = __builtin_amdgcn_mfma_f32_16x16x16bf16_1k(af[c], bf, acc, 0, 0, 0);
    }
    int dm = 16 * n + l15;
    if (dm < DMODEL) {
#pragma unroll
      for (int r = 0; r < 4; ++r) {
        int rr = sbase + 4 * g + r;
        out[(size_t)rr * DMODEL + dm] = acc[r];
      }
    }
  }
}

extern "C" void kernel_launch(void* const* d_in, const int* in_sizes, int n_in,
                              void* d_out, int out_size, void* d_ws, size_t ws_size,
                              hipStream_t stream) {
  const float* q = (const float*)d_in[0];
  const float* k = (const float*)d_in[1];
  const float* v = (const float*)d_in[2];
  const float* WQ = (const float*)d_in[3];
  const float* WK = (const float*)d_in[4];
  const float* WV = (const float*)d_in[5];
  const float* WO = (const float*)d_in[6];
  float* out = (float*)d_out;
  char* ws = (char*)d_ws;

  const size_t MB2 = 2097152;  // 16384*64*2 bytes
  const size_t NR = (size_t)NB * SLEN;
  // KV-split 8 (bf16 partials); fall back to 4 if workspace is tight
  auto need = [&](int n) {
    return (size_t)131072 + 3 * MB2 + (size_t)n * NR * 4 + (size_t)n * NR * HP * 2;
  };
  int nsplit = (ws_size >= need(8)) ? 8 : 4;

  short* wot = (short*)(ws + 98304);
  short* Qp = (short*)(ws + 131072);
  short* Kp = (short*)(ws + 131072 + MB2);
  short* VpT = (short*)(ws + 131072 + 2 * MB2);
  float* Lp = (float*)(ws + 131072 + 3 * MB2);
  short* Opb = (short*)(Lp + nsplit * NR);

  proj_kernel<<<dim3(256, 1, 4), dim3(256), 0, stream>>>(q, k, v, WQ, WK, WV, WO,
                                                          Qp, Kp, VpT, wot);
  attn_kernel<<<dim3(32, NB, nsplit), dim3(256), 0, stream>>>(Qp, Kp, VpT, Lp, Opb);
  if (nsplit == 8)
    combineproj_kernel<8><<<dim3(256), dim3(256), 0, stream>>>(Lp, Opb, wot, out);
  else
    combineproj_kernel<4><<<dim3(256), dim3(256), 0, stream>>>(Lp, Opb, wot, out);
}

// Round 18
// 62.068 us; speedup vs baseline: 2.0562x; 2.0562x over previous
//
#include <hip/hip_runtime.h>
#include <hip/hip_bf16.h>

// Problem: B=4, S=4096, D_MODEL=200, head=50 (padded to 64), out fp32.
// Pipeline: proj (MFMA, coalesced LDS staging + coalesced VpT transpose-store)
//           -> flash attn (MFMA, KV-split 8, ping-pong LDS, 2 q-tiles/wave,
//           K=32 QK^T, fixed-exponent softmax, bf16 partials) -> fused
//           combine+outproj (MFMA).
// R15: launch_bounds(256,5) -> VGPR-48 spills -> 2x regression. Ceiling: 4/CU.
// R17: direct-L2 attn (no LDS) -> 3x regression; LDS staging is the latency
// decoupler, not overhead. R16 attn structure is final.

typedef short s4 __attribute__((ext_vector_type(4)));
typedef short s8 __attribute__((ext_vector_type(8)));
typedef float f4 __attribute__((ext_vector_type(4)));
typedef unsigned u2 __attribute__((ext_vector_type(2)));

#define SLEN 4096
#define NB 4
#define DMODEL 200
#define HREAL 50
#define HP 64
#define DMP 208
#define XPAD 212
#define KVB 64
// (1/sqrt(50)) * log2(e) folded into WQ so softmax uses exp2 (v_exp_f32)
#define QSCALE 0.20402789f
// Fixed softmax exponent offset (log2 units); softmax is shift-invariant.
#define MFIX 24.0f

__device__ __forceinline__ short f2bf(float f) {
  unsigned u = __builtin_bit_cast(unsigned, f);
  u += 0x7FFFu + ((u >> 16) & 1u);
  return (short)(u >> 16);
}

__device__ __forceinline__ float bf2f(short s) {
  unsigned u = ((unsigned)(unsigned short)s) << 16;
  return __builtin_bit_cast(float, u);
}

__device__ __forceinline__ float fexp2(float x) { return __builtin_amdgcn_exp2f(x); }

// ---------------- projections: X[16384,200] @ W -> bf16 [16384,64] -----------
// mode 0: q->Qp (scaled), 1: k->Kp, 2: v->VpT (transposed store [B][64][S],
// via LDS transpose -> fully coalesced 8B-chunk writes), mode 3: build wot.
__global__ __launch_bounds__(256) void proj_kernel(
    const float* __restrict__ q, const float* __restrict__ k, const float* __restrict__ v,
    const float* __restrict__ WQ, const float* __restrict__ WK, const float* __restrict__ WV,
    const float* __restrict__ WO, short* __restrict__ Qp, short* __restrict__ Kp,
    short* __restrict__ VpT, short* __restrict__ wot) {
  const int mode = blockIdx.z;
  const int tid = threadIdx.x;
  if (mode == 3) {  // wot: 13312 entries over 52 blocks
    int id = blockIdx.x * 256 + tid;
    if (blockIdx.x < 52 && id < DMP * HP) {
      int dm = id / HP, e = id % HP;
      float vv = 0.f;
      if (dm < DMODEL && e < HREAL) {
        vv = WO[(e)*DMODEL + dm] + WO[(HREAL + e) * DMODEL + dm] +
             WO[(2 * HREAL + e) * DMODEL + dm] + WO[(3 * HREAL + e) * DMODEL + dm];
      }
      wot[dm * HP + e] = f2bf(vv);
    }
    return;
  }
  __shared__ __align__(16) short Xl[64 * XPAD];
  __shared__ __align__(16) short Wl[64 * XPAD];
  const float* X = (mode == 0) ? q : (mode == 1 ? k : v);
  const float* Wsrc = (mode == 0) ? WQ : (mode == 1 ? WK : WV);
  const int sb64 = blockIdx.x * 64;

  {
    // ---- stage X: 3200 contiguous f4 chunks (rows of 50) ----
    const f4* src = (const f4*)(X + (size_t)sb64 * DMODEL);
#pragma unroll
    for (int i = 0; i < 13; ++i) {
      int idx = tid + i * 256;
      if (idx < 3200) {
        f4 a = src[idx];
        int row = idx / 50, c = idx - row * 50;
        s4 bv;
#pragma unroll
        for (int j = 0; j < 4; ++j) bv[j] = f2bf(a[j]);
        *(s4*)(Xl + row * XPAD + c * 4) = bv;
      }
    }
    s4 z = {0, 0, 0, 0};
    if (tid < 192) {  // zero X pad cols 200..211
      int row = tid / 3, c = 200 + (tid - (tid / 3) * 3) * 4;
      *(s4*)(Xl + row * XPAD + c) = z;
    }
    // ---- transpose W [200][50] fp32 -> Wl[e][d] bf16 (e<50, d<200) ----
#pragma unroll
    for (int i = 0; i < 40; ++i) {
      int flat = tid + i * 256;
      if (flat < DMODEL * HREAL) {
        float vv = Wsrc[flat];
        int d = flat / HREAL, e = flat - HREAL * d;
        if (mode == 0) vv *= QSCALE;
        Wl[e * XPAD + d] = f2bf(vv);
      }
    }
    // ---- W pad zero (disjoint from transpose writes) ----
#pragma unroll
    for (int i = 0; i < 3; ++i) {  // rows 50..63, all cols: 742 s4 chunks
      int idx = tid + i * 256;
      if (idx < 742) *(s4*)(Wl + 50 * XPAD + idx * 4) = z;
    }
    if (tid < 150) {  // rows 0..49, cols 200..211: 150 s4 chunks
      int row = tid / 3, c = 200 + (tid - (tid / 3) * 3) * 4;
      *(s4*)(Wl + row * XPAD + c) = z;
    }
  }
  __syncthreads();

  const int lane = tid & 63, wid = tid >> 6;
  const int l15 = lane & 15, g = lane >> 4;
  const int row16 = wid * 16 + l15;
  const int sbase = sb64 + wid * 16;
  f4 acc[4] = {};
#pragma unroll
  for (int c = 0; c < 13; ++c) {
    int d0 = 16 * c + 4 * g;
    s4 af = *(const s4*)(Xl + row16 * XPAD + d0);
#pragma unroll
    for (int n = 0; n < 4; ++n) {
      s4 bf = *(const s4*)(Wl + (16 * n + l15) * XPAD + d0);
      acc[n] = __builtin_amdgcn_mfma_f32_16x16x16bf16_1k(af, bf, acc[n], 0, 0, 0);
    }
  }
  if (mode < 2) {
    short* OUT = (mode == 0) ? Qp : Kp;
#pragma unroll
    for (int n = 0; n < 4; ++n)
#pragma unroll
      for (int r = 0; r < 4; ++r) {
        int rr = sbase + 4 * g + r;
        OUT[rr * HP + 16 * n + l15] = f2bf(acc[n][r]);
      }
  } else {
    // V: transpose in LDS (reuse Xl as Vl[64 d][68 pad]) -> coalesced stores
    __syncthreads();  // all Xl/Wl MFMA reads complete
    short* Vl = Xl;
#pragma unroll
    for (int n = 0; n < 4; ++n)
#pragma unroll
      for (int r = 0; r < 4; ++r) {
        int ls = wid * 16 + 4 * g + r;      // local s (0..63)
        Vl[(16 * n + l15) * 68 + ls] = f2bf(acc[n][r]);
      }
    __syncthreads();
    const int bb = sb64 >> 12;
    const int s0 = sb64 & 4095;
#pragma unroll
    for (int i = 0; i < 4; ++i) {
      int idx = tid + i * 256;          // 0..1023
      int d = idx >> 4, ch = idx & 15;  // row d, 8B chunk
      s4 vv = *(const s4*)(Vl + d * 68 + ch * 4);
      *(s4*)(VpT + ((size_t)(bb * HP + d)) * SLEN + s0 + ch * 4) = vv;
    }
  }
}

// ---------------- flash attention, swapped-operand QK^T, KV-split ------------
// LDS content: linear dest, inverse-swizzled global source (involution xor of
// byte bits 4-6 with row&7). Reads apply the same xor -> conflict-free.
// Ping-pong double buffer, single barrier/step. QK^T = native gfx950 K=32
// MFMA. Fixed-exponent softmax (branch-free).
__global__ __launch_bounds__(256, 4) void attn_kernel(
    const short* __restrict__ Qp, const short* __restrict__ Kp,
    const short* __restrict__ VpT, float* __restrict__ Lp,
    short* __restrict__ Opb) {
  __shared__ __align__(16) char Klds[2][KVB * 128];  // 2 x 8KB, swizzled
  __shared__ __align__(16) char Vlds[2][HP * 128];   // 2 x 8KB, swizzled
  const int tid = threadIdx.x;
  const int lane = tid & 63, wid = tid >> 6;
  const int l15 = lane & 15, g = lane >> 4;
  const int b = blockIdx.y, z = blockIdx.z;
  const int nsplit = gridDim.z;
  const int qrowA = blockIdx.x * 128 + wid * 32 + l15;
  const int qrowB = qrowA + 16;
  const int ksw = (l15 & 7) << 4;

  // Q fragments for K=32 MFMA: lane group g holds d 8g..8g+7 (+32 for frag 1)
  s8 qfA[2], qfB[2];
  {
    const short* qpa = Qp + (size_t)(b * SLEN + qrowA) * HP + 8 * g;
    const short* qpb = Qp + (size_t)(b * SLEN + qrowB) * HP + 8 * g;
    qfA[0] = *(const s8*)(qpa);
    qfA[1] = *(const s8*)(qpa + 32);
    qfB[0] = *(const s8*)(qpb);
    qfB[1] = *(const s8*)(qpb + 32);
  }

  // LDS read base offsets (bytes), loop-invariant; inner addr = base + tt*2048
  const int kr0 = l15 * 128 + ((16 * g) ^ ksw);
  const int kr1 = l15 * 128 + ((64 + 16 * g) ^ ksw);
  const int vb = l15 * 128 + ((8 * g) ^ ksw);

  // staging: linear LDS slot cj <- global slot ci = cj ^ (row&7)
  const int cj0 = tid, cj1 = tid + 256;
  const int ci0 = (cj0 ^ ((cj0 >> 3) & 7)) * 16;
  const int ci1 = (cj1 ^ ((cj1 >> 3) & 7)) * 16;
  const int d0 = cj0 >> 3, d1 = cj1 >> 3;
  const int ch0 = ((cj0 & 7) ^ (d0 & 7)) * 16;
  const int ch1 = ((cj1 & 7) ^ (d1 & 7)) * 16;

  const int kv0 = z * (SLEN / nsplit);
  const char* kp0 = (const char*)Kp + (size_t)(b * SLEN + kv0) * 128 + ci0;
  const char* kp1 = (const char*)Kp + (size_t)(b * SLEN + kv0) * 128 + ci1;
  const char* vp0 =
      (const char*)VpT + ((size_t)(b * HP + d0) * SLEN + kv0) * 2 + ch0;
  const char* vp1 =
      (const char*)VpT + ((size_t)(b * HP + d1) * SLEN + kv0) * 2 + ch1;

  // prologue: load tile 0 and stage into buffer 0
  {
    f4 k0 = *(const f4*)kp0;
    f4 k1 = *(const f4*)kp1;
    f4 v0 = *(const f4*)vp0;
    f4 v1 = *(const f4*)vp1;
    *(f4*)(Klds[0] + tid * 16) = k0;
    *(f4*)(Klds[0] + tid * 16 + 4096) = k1;
    *(f4*)(Vlds[0] + tid * 16) = v0;
    *(f4*)(Vlds[0] + tid * 16 + 4096) = v1;
    kp0 += KVB * 128;
    kp1 += KVB * 128;
    vp0 += KVB * 2;
    vp1 += KVB * 2;
  }

  f4 oA[4] = {}, oB[4] = {};
  float lsumA = 0.f, lsumB = 0.f;
  const int nsteps = SLEN / nsplit / KVB;
  for (int step = 0; step < nsteps; ++step) {
    const int p = step & 1;
    f4 rk0, rk1, rv0, rv1;
    const bool more = (step + 1 < nsteps);
    if (more) {  // issue next-tile loads; consumed after compute
      rk0 = *(const f4*)kp0;
      rk1 = *(const f4*)kp1;
      rv0 = *(const f4*)vp0;
      rv1 = *(const f4*)vp1;
      kp0 += KVB * 128;
      kp1 += KVB * 128;
      vp0 += KVB * 2;
      vp1 += KVB * 2;
    }
    __syncthreads();  // buf[p] staged (prev iter / prologue) -> visible
    const char* Kbuf = Klds[p];
    const char* Vbuf = Vlds[p];
#pragma unroll
    for (int tt = 0; tt < 4; ++tt) {
      // S^T tile [16 keys x 16 q] = K_tile . Q^T  (C: col=q=l15, row=key=4g+r)
      f4 stA, stB;
      {
        s8 kf0 = *(const s8*)(Kbuf + kr0 + tt * 2048);
        s8 kf1 = *(const s8*)(Kbuf + kr1 + tt * 2048);
        __builtin_amdgcn_s_setprio(1);
        stA = __builtin_amdgcn_mfma_f32_16x16x32_bf16(kf0, qfA[0], (f4){}, 0, 0, 0);
        stB = __builtin_amdgcn_mfma_f32_16x16x32_bf16(kf0, qfB[0], (f4){}, 0, 0, 0);
        stA = __builtin_amdgcn_mfma_f32_16x16x32_bf16(kf1, qfA[1], stA, 0, 0, 0);
        stB = __builtin_amdgcn_mfma_f32_16x16x32_bf16(kf1, qfB[1], stB, 0, 0, 0);
        __builtin_amdgcn_s_setprio(0);
      }
      // ---- fixed-exponent softmax (branch-free) ----
      float pa0 = fexp2(stA[0] - MFIX), pa1 = fexp2(stA[1] - MFIX);
      float pa2 = fexp2(stA[2] - MFIX), pa3 = fexp2(stA[3] - MFIX);
      lsumA += (pa0 + pa1) + (pa2 + pa3);
      union { unsigned u[2]; s4 s; } puA;
      asm("v_cvt_pk_bf16_f32 %0, %1, %2" : "=v"(puA.u[0]) : "v"(pa0), "v"(pa1));
      asm("v_cvt_pk_bf16_f32 %0, %1, %2" : "=v"(puA.u[1]) : "v"(pa2), "v"(pa3));
      s4 pfA = puA.s;
      float pb0 = fexp2(stB[0] - MFIX), pb1 = fexp2(stB[1] - MFIX);
      float pb2 = fexp2(stB[2] - MFIX), pb3 = fexp2(stB[3] - MFIX);
      lsumB += (pb0 + pb1) + (pb2 + pb3);
      union { unsigned u[2]; s4 s; } puB;
      asm("v_cvt_pk_bf16_f32 %0, %1, %2" : "=v"(puB.u[0]) : "v"(pb0), "v"(pb1));
      asm("v_cvt_pk_bf16_f32 %0, %1, %2" : "=v"(puB.u[1]) : "v"(pb2), "v"(pb3));
      s4 pfB = puB.s;
      // O^T[d][q] += V^T . P  (P already in B-frag layout: col=q=l15, k=4g+r)
      const char* vrow = Vbuf + (vb ^ (tt << 5));
      __builtin_amdgcn_s_setprio(1);
#pragma unroll
      for (int n = 0; n < 4; ++n) {
        s4 vf = *(const s4*)(vrow + n * 2048);
        oA[n] = __builtin_amdgcn_mfma_f32_16x16x16bf16_1k(vf, pfA, oA[n], 0, 0, 0);
        oB[n] = __builtin_amdgcn_mfma_f32_16x16x16bf16_1k(vf, pfB, oB[n], 0, 0, 0);
      }
      __builtin_amdgcn_s_setprio(0);
    }
    if (more) {  // stage next tile into the other buffer
      *(f4*)(Klds[p ^ 1] + tid * 16) = rk0;
      *(f4*)(Klds[p ^ 1] + tid * 16 + 4096) = rk1;
      *(f4*)(Vlds[p ^ 1] + tid * 16) = rv0;
      *(f4*)(Vlds[p ^ 1] + tid * 16 + 4096) = rv1;
    }
  }
  lsumA += __shfl_xor(lsumA, 16);
  lsumA += __shfl_xor(lsumA, 32);
  lsumB += __shfl_xor(lsumB, 16);
  lsumB += __shfl_xor(lsumB, 32);
  const int rowgA = b * SLEN + qrowA;
  const int rowgB = b * SLEN + qrowB;
  const int NR = NB * SLEN;
  if (lane < 16) {
    Lp[z * NR + rowgA] = lsumA;
    Lp[z * NR + rowgB] = lsumB;
  }
  // bf16 partial store (cvt_pk): halves split traffic
  short* opA = Opb + ((size_t)z * NR + rowgA) * HP;
  short* opB = Opb + ((size_t)z * NR + rowgB) * HP;
#pragma unroll
  for (int n = 0; n < 4; ++n) {
    u2 ua, ub;
    asm("v_cvt_pk_bf16_f32 %0, %1, %2" : "=v"(ua[0]) : "v"(oA[n][0]), "v"(oA[n][1]));
    asm("v_cvt_pk_bf16_f32 %0, %1, %2" : "=v"(ua[1]) : "v"(oA[n][2]), "v"(oA[n][3]));
    asm("v_cvt_pk_bf16_f32 %0, %1, %2" : "=v"(ub[0]) : "v"(oB[n][0]), "v"(oB[n][1]));
    asm("v_cvt_pk_bf16_f32 %0, %1, %2" : "=v"(ub[1]) : "v"(oB[n][2]), "v"(oB[n][3]));
    *(u2*)(opA + 16 * n + 4 * g) = ua;
    *(u2*)(opB + 16 * n + 4 * g) = ub;
  }
}

// ------- fused: merge KV-split partials (plain sums) + out-projection --------
template <int NSPLIT>
__global__ __launch_bounds__(256) void combineproj_kernel(
    const float* __restrict__ Lp, const short* __restrict__ Opb,
    const short* __restrict__ wot, float* __restrict__ out) {
  const int lane = threadIdx.x & 63, wid = threadIdx.x >> 6;
  const int l15 = lane & 15, g = lane >> 4;
  const int sbase = blockIdx.x * 64 + wid * 16;
  const int row = sbase + l15;
  const int NR = NB * SLEN;
  float L = 0.f;
#pragma unroll
  for (int s = 0; s < NSPLIT; ++s) L += Lp[s * NR + row];
  float inv = 1.0f / L;
  s4 af[4];
#pragma unroll
  for (int c = 0; c < 4; ++c) {
    f4 acc = {};
#pragma unroll
    for (int s = 0; s < NSPLIT; ++s) {
      s4 sv = *(const s4*)(Opb + ((size_t)s * NR + row) * HP + 16 * c + 4 * g);
      acc[0] += bf2f(sv[0]);
      acc[1] += bf2f(sv[1]);
      acc[2] += bf2f(sv[2]);
      acc[3] += bf2f(sv[3]);
    }
#pragma unroll
    for (int r = 0; r < 4; ++r) af[c][r] = f2bf(acc[r] * inv);
  }
  for (int n = 0; n < 13; ++n) {
    f4 acc = {};
    const short* brow = wot + (16 * n + l15) * HP + 4 * g;
#pragma unroll
    for (int c = 0; c < 4; ++c) {
      s4 bf = *(const s4*)(brow + 16 * c);
      acc = __builtin_amdgcn_mfma_f32_16x16x16bf16_1k(af[c], bf, acc, 0, 0, 0);
    }
    int dm = 16 * n + l15;
    if (dm < DMODEL) {
#pragma unroll
      for (int r = 0; r < 4; ++r) {
        int rr = sbase + 4 * g + r;
        out[(size_t)rr * DMODEL + dm] = acc[r];
      }
    }
  }
}

extern "C" void kernel_launch(void* const* d_in, const int* in_sizes, int n_in,
                              void* d_out, int out_size, void* d_ws, size_t ws_size,
                              hipStream_t stream) {
  const float* q = (const float*)d_in[0];
  const float* k = (const float*)d_in[1];
  const float* v = (const float*)d_in[2];
  const float* WQ = (const float*)d_in[3];
  const float* WK = (const float*)d_in[4];
  const float* WV = (const float*)d_in[5];
  const float* WO = (const float*)d_in[6];
  float* out = (float*)d_out;
  char* ws = (char*)d_ws;

  const size_t MB2 = 2097152;  // 16384*64*2 bytes
  const size_t NR = (size_t)NB * SLEN;
  // KV-split 8 (bf16 partials); fall back to 4 if workspace is tight
  auto need = [&](int n) {
    return (size_t)131072 + 3 * MB2 + (size_t)n * NR * 4 + (size_t)n * NR * HP * 2;
  };
  int nsplit = (ws_size >= need(8)) ? 8 : 4;

  short* wot = (short*)(ws + 98304);
  short* Qp = (short*)(ws + 131072);
  short* Kp = (short*)(ws + 131072 + MB2);
  short* VpT = (short*)(ws + 131072 + 2 * MB2);
  float* Lp = (float*)(ws + 131072 + 3 * MB2);
  short* Opb = (short*)(Lp + nsplit * NR);

  proj_kernel<<<dim3(256, 1, 4), dim3(256), 0, stream>>>(q, k, v, WQ, WK, WV, WO,
                                                          Qp, Kp, VpT, wot);
  attn_kernel<<<dim3(32, NB, nsplit), dim3(256), 0, stream>>>(Qp, Kp, VpT, Lp, Opb);
  if (nsplit == 8)
    combineproj_kernel<8><<<dim3(256), dim3(256), 0, stream>>>(Lp, Opb, wot, out);
  else
    combineproj_kernel<4><<<dim3(256), dim3(256), 0, stream>>>(Lp, Opb, wot, out);
}

// Round 19
// 61.474 us; speedup vs baseline: 2.0760x; 1.0097x over previous
//
#include <hip/hip_runtime.h>
#include <hip/hip_bf16.h>

// Problem: B=4, S=4096, D_MODEL=200, head=50 (padded to 64), out fp32.
// Pipeline: proj (MFMA, coalesced LDS staging + coalesced VpT transpose-store)
//           -> flash attn (MFMA, KV-split 8, ping-pong LDS, 2 q-tiles/wave,
//           K=32 QK^T, fixed-exponent softmax, bf16 partials, NO setprio) ->
//           fused combine+outproj (MFMA).
// R15: launch_bounds(256,5) -> VGPR-48 spills -> 2x regression. Ceiling: 4/CU.
// R17: direct-L2 attn (no LDS) -> 3x regression; LDS staging is the latency
// decoupler. R19: isolated ablation of s_setprio (entered bundled in R6;
// m190 says it HURTS barrier-synced lockstep kernels, which ours now is).

typedef short s4 __attribute__((ext_vector_type(4)));
typedef short s8 __attribute__((ext_vector_type(8)));
typedef float f4 __attribute__((ext_vector_type(4)));
typedef unsigned u2 __attribute__((ext_vector_type(2)));

#define SLEN 4096
#define NB 4
#define DMODEL 200
#define HREAL 50
#define HP 64
#define DMP 208
#define XPAD 212
#define KVB 64
// (1/sqrt(50)) * log2(e) folded into WQ so softmax uses exp2 (v_exp_f32)
#define QSCALE 0.20402789f
// Fixed softmax exponent offset (log2 units); softmax is shift-invariant.
#define MFIX 24.0f

__device__ __forceinline__ short f2bf(float f) {
  unsigned u = __builtin_bit_cast(unsigned, f);
  u += 0x7FFFu + ((u >> 16) & 1u);
  return (short)(u >> 16);
}

__device__ __forceinline__ float bf2f(short s) {
  unsigned u = ((unsigned)(unsigned short)s) << 16;
  return __builtin_bit_cast(float, u);
}

__device__ __forceinline__ float fexp2(float x) { return __builtin_amdgcn_exp2f(x); }

// ---------------- projections: X[16384,200] @ W -> bf16 [16384,64] -----------
// mode 0: q->Qp (scaled), 1: k->Kp, 2: v->VpT (transposed store [B][64][S],
// via LDS transpose -> fully coalesced 8B-chunk writes), mode 3: build wot.
__global__ __launch_bounds__(256) void proj_kernel(
    const float* __restrict__ q, const float* __restrict__ k, const float* __restrict__ v,
    const float* __restrict__ WQ, const float* __restrict__ WK, const float* __restrict__ WV,
    const float* __restrict__ WO, short* __restrict__ Qp, short* __restrict__ Kp,
    short* __restrict__ VpT, short* __restrict__ wot) {
  const int mode = blockIdx.z;
  const int tid = threadIdx.x;
  if (mode == 3) {  // wot: 13312 entries over 52 blocks
    int id = blockIdx.x * 256 + tid;
    if (blockIdx.x < 52 && id < DMP * HP) {
      int dm = id / HP, e = id % HP;
      float vv = 0.f;
      if (dm < DMODEL && e < HREAL) {
        vv = WO[(e)*DMODEL + dm] + WO[(HREAL + e) * DMODEL + dm] +
             WO[(2 * HREAL + e) * DMODEL + dm] + WO[(3 * HREAL + e) * DMODEL + dm];
      }
      wot[dm * HP + e] = f2bf(vv);
    }
    return;
  }
  __shared__ __align__(16) short Xl[64 * XPAD];
  __shared__ __align__(16) short Wl[64 * XPAD];
  const float* X = (mode == 0) ? q : (mode == 1 ? k : v);
  const float* Wsrc = (mode == 0) ? WQ : (mode == 1 ? WK : WV);
  const int sb64 = blockIdx.x * 64;

  {
    // ---- stage X: 3200 contiguous f4 chunks (rows of 50) ----
    const f4* src = (const f4*)(X + (size_t)sb64 * DMODEL);
#pragma unroll
    for (int i = 0; i < 13; ++i) {
      int idx = tid + i * 256;
      if (idx < 3200) {
        f4 a = src[idx];
        int row = idx / 50, c = idx - row * 50;
        s4 bv;
#pragma unroll
        for (int j = 0; j < 4; ++j) bv[j] = f2bf(a[j]);
        *(s4*)(Xl + row * XPAD + c * 4) = bv;
      }
    }
    s4 z = {0, 0, 0, 0};
    if (tid < 192) {  // zero X pad cols 200..211
      int row = tid / 3, c = 200 + (tid - (tid / 3) * 3) * 4;
      *(s4*)(Xl + row * XPAD + c) = z;
    }
    // ---- transpose W [200][50] fp32 -> Wl[e][d] bf16 (e<50, d<200) ----
#pragma unroll
    for (int i = 0; i < 40; ++i) {
      int flat = tid + i * 256;
      if (flat < DMODEL * HREAL) {
        float vv = Wsrc[flat];
        int d = flat / HREAL, e = flat - HREAL * d;
        if (mode == 0) vv *= QSCALE;
        Wl[e * XPAD + d] = f2bf(vv);
      }
    }
    // ---- W pad zero (disjoint from transpose writes) ----
#pragma unroll
    for (int i = 0; i < 3; ++i) {  // rows 50..63, all cols: 742 s4 chunks
      int idx = tid + i * 256;
      if (idx < 742) *(s4*)(Wl + 50 * XPAD + idx * 4) = z;
    }
    if (tid < 150) {  // rows 0..49, cols 200..211: 150 s4 chunks
      int row = tid / 3, c = 200 + (tid - (tid / 3) * 3) * 4;
      *(s4*)(Wl + row * XPAD + c) = z;
    }
  }
  __syncthreads();

  const int lane = tid & 63, wid = tid >> 6;
  const int l15 = lane & 15, g = lane >> 4;
  const int row16 = wid * 16 + l15;
  const int sbase = sb64 + wid * 16;
  f4 acc[4] = {};
#pragma unroll
  for (int c = 0; c < 13; ++c) {
    int d0 = 16 * c + 4 * g;
    s4 af = *(const s4*)(Xl + row16 * XPAD + d0);
#pragma unroll
    for (int n = 0; n < 4; ++n) {
      s4 bf = *(const s4*)(Wl + (16 * n + l15) * XPAD + d0);
      acc[n] = __builtin_amdgcn_mfma_f32_16x16x16bf16_1k(af, bf, acc[n], 0, 0, 0);
    }
  }
  if (mode < 2) {
    short* OUT = (mode == 0) ? Qp : Kp;
#pragma unroll
    for (int n = 0; n < 4; ++n)
#pragma unroll
      for (int r = 0; r < 4; ++r) {
        int rr = sbase + 4 * g + r;
        OUT[rr * HP + 16 * n + l15] = f2bf(acc[n][r]);
      }
  } else {
    // V: transpose in LDS (reuse Xl as Vl[64 d][68 pad]) -> coalesced stores
    __syncthreads();  // all Xl/Wl MFMA reads complete
    short* Vl = Xl;
#pragma unroll
    for (int n = 0; n < 4; ++n)
#pragma unroll
      for (int r = 0; r < 4; ++r) {
        int ls = wid * 16 + 4 * g + r;      // local s (0..63)
        Vl[(16 * n + l15) * 68 + ls] = f2bf(acc[n][r]);
      }
    __syncthreads();
    const int bb = sb64 >> 12;
    const int s0 = sb64 & 4095;
#pragma unroll
    for (int i = 0; i < 4; ++i) {
      int idx = tid + i * 256;          // 0..1023
      int d = idx >> 4, ch = idx & 15;  // row d, 8B chunk
      s4 vv = *(const s4*)(Vl + d * 68 + ch * 4);
      *(s4*)(VpT + ((size_t)(bb * HP + d)) * SLEN + s0 + ch * 4) = vv;
    }
  }
}

// ---------------- flash attention, swapped-operand QK^T, KV-split ------------
// LDS content: linear dest, inverse-swizzled global source (involution xor of
// byte bits 4-6 with row&7). Reads apply the same xor -> conflict-free.
// Ping-pong double buffer, single barrier/step. QK^T = native gfx950 K=32
// MFMA. Fixed-exponent softmax (branch-free). No setprio (R19 ablation).
__global__ __launch_bounds__(256, 4) void attn_kernel(
    const short* __restrict__ Qp, const short* __restrict__ Kp,
    const short* __restrict__ VpT, float* __restrict__ Lp,
    short* __restrict__ Opb) {
  __shared__ __align__(16) char Klds[2][KVB * 128];  // 2 x 8KB, swizzled
  __shared__ __align__(16) char Vlds[2][HP * 128];   // 2 x 8KB, swizzled
  const int tid = threadIdx.x;
  const int lane = tid & 63, wid = tid >> 6;
  const int l15 = lane & 15, g = lane >> 4;
  const int b = blockIdx.y, z = blockIdx.z;
  const int nsplit = gridDim.z;
  const int qrowA = blockIdx.x * 128 + wid * 32 + l15;
  const int qrowB = qrowA + 16;
  const int ksw = (l15 & 7) << 4;

  // Q fragments for K=32 MFMA: lane group g holds d 8g..8g+7 (+32 for frag 1)
  s8 qfA[2], qfB[2];
  {
    const short* qpa = Qp + (size_t)(b * SLEN + qrowA) * HP + 8 * g;
    const short* qpb = Qp + (size_t)(b * SLEN + qrowB) * HP + 8 * g;
    qfA[0] = *(const s8*)(qpa);
    qfA[1] = *(const s8*)(qpa + 32);
    qfB[0] = *(const s8*)(qpb);
    qfB[1] = *(const s8*)(qpb + 32);
  }

  // LDS read base offsets (bytes), loop-invariant; inner addr = base + tt*2048
  const int kr0 = l15 * 128 + ((16 * g) ^ ksw);
  const int kr1 = l15 * 128 + ((64 + 16 * g) ^ ksw);
  const int vb = l15 * 128 + ((8 * g) ^ ksw);

  // staging: linear LDS slot cj <- global slot ci = cj ^ (row&7)
  const int cj0 = tid, cj1 = tid + 256;
  const int ci0 = (cj0 ^ ((cj0 >> 3) & 7)) * 16;
  const int ci1 = (cj1 ^ ((cj1 >> 3) & 7)) * 16;
  const int d0 = cj0 >> 3, d1 = cj1 >> 3;
  const int ch0 = ((cj0 & 7) ^ (d0 & 7)) * 16;
  const int ch1 = ((cj1 & 7) ^ (d1 & 7)) * 16;

  const int kv0 = z * (SLEN / nsplit);
  const char* kp0 = (const char*)Kp + (size_t)(b * SLEN + kv0) * 128 + ci0;
  const char* kp1 = (const char*)Kp + (size_t)(b * SLEN + kv0) * 128 + ci1;
  const char* vp0 =
      (const char*)VpT + ((size_t)(b * HP + d0) * SLEN + kv0) * 2 + ch0;
  const char* vp1 =
      (const char*)VpT + ((size_t)(b * HP + d1) * SLEN + kv0) * 2 + ch1;

  // prologue: load tile 0 and stage into buffer 0
  {
    f4 k0 = *(const f4*)kp0;
    f4 k1 = *(const f4*)kp1;
    f4 v0 = *(const f4*)vp0;
    f4 v1 = *(const f4*)vp1;
    *(f4*)(Klds[0] + tid * 16) = k0;
    *(f4*)(Klds[0] + tid * 16 + 4096) = k1;
    *(f4*)(Vlds[0] + tid * 16) = v0;
    *(f4*)(Vlds[0] + tid * 16 + 4096) = v1;
    kp0 += KVB * 128;
    kp1 += KVB * 128;
    vp0 += KVB * 2;
    vp1 += KVB * 2;
  }

  f4 oA[4] = {}, oB[4] = {};
  float lsumA = 0.f, lsumB = 0.f;
  const int nsteps = SLEN / nsplit / KVB;
  for (int step = 0; step < nsteps; ++step) {
    const int p = step & 1;
    f4 rk0, rk1, rv0, rv1;
    const bool more = (step + 1 < nsteps);
    if (more) {  // issue next-tile loads; consumed after compute
      rk0 = *(const f4*)kp0;
      rk1 = *(const f4*)kp1;
      rv0 = *(const f4*)vp0;
      rv1 = *(const f4*)vp1;
      kp0 += KVB * 128;
      kp1 += KVB * 128;
      vp0 += KVB * 2;
      vp1 += KVB * 2;
    }
    __syncthreads();  // buf[p] staged (prev iter / prologue) -> visible
    const char* Kbuf = Klds[p];
    const char* Vbuf = Vlds[p];
#pragma unroll
    for (int tt = 0; tt < 4; ++tt) {
      // S^T tile [16 keys x 16 q] = K_tile . Q^T  (C: col=q=l15, row=key=4g+r)
      f4 stA, stB;
      {
        s8 kf0 = *(const s8*)(Kbuf + kr0 + tt * 2048);
        s8 kf1 = *(const s8*)(Kbuf + kr1 + tt * 2048);
        stA = __builtin_amdgcn_mfma_f32_16x16x32_bf16(kf0, qfA[0], (f4){}, 0, 0, 0);
        stB = __builtin_amdgcn_mfma_f32_16x16x32_bf16(kf0, qfB[0], (f4){}, 0, 0, 0);
        stA = __builtin_amdgcn_mfma_f32_16x16x32_bf16(kf1, qfA[1], stA, 0, 0, 0);
        stB = __builtin_amdgcn_mfma_f32_16x16x32_bf16(kf1, qfB[1], stB, 0, 0, 0);
      }
      // ---- fixed-exponent softmax (branch-free) ----
      float pa0 = fexp2(stA[0] - MFIX), pa1 = fexp2(stA[1] - MFIX);
      float pa2 = fexp2(stA[2] - MFIX), pa3 = fexp2(stA[3] - MFIX);
      lsumA += (pa0 + pa1) + (pa2 + pa3);
      union { unsigned u[2]; s4 s; } puA;
      asm("v_cvt_pk_bf16_f32 %0, %1, %2" : "=v"(puA.u[0]) : "v"(pa0), "v"(pa1));
      asm("v_cvt_pk_bf16_f32 %0, %1, %2" : "=v"(puA.u[1]) : "v"(pa2), "v"(pa3));
      s4 pfA = puA.s;
      float pb0 = fexp2(stB[0] - MFIX), pb1 = fexp2(stB[1] - MFIX);
      float pb2 = fexp2(stB[2] - MFIX), pb3 = fexp2(stB[3] - MFIX);
      lsumB += (pb0 + pb1) + (pb2 + pb3);
      union { unsigned u[2]; s4 s; } puB;
      asm("v_cvt_pk_bf16_f32 %0, %1, %2" : "=v"(puB.u[0]) : "v"(pb0), "v"(pb1));
      asm("v_cvt_pk_bf16_f32 %0, %1, %2" : "=v"(puB.u[1]) : "v"(pb2), "v"(pb3));
      s4 pfB = puB.s;
      // O^T[d][q] += V^T . P  (P already in B-frag layout: col=q=l15, k=4g+r)
      const char* vrow = Vbuf + (vb ^ (tt << 5));
#pragma unroll
      for (int n = 0; n < 4; ++n) {
        s4 vf = *(const s4*)(vrow + n * 2048);
        oA[n] = __builtin_amdgcn_mfma_f32_16x16x16bf16_1k(vf, pfA, oA[n], 0, 0, 0);
        oB[n] = __builtin_amdgcn_mfma_f32_16x16x16bf16_1k(vf, pfB, oB[n], 0, 0, 0);
      }
    }
    if (more) {  // stage next tile into the other buffer
      *(f4*)(Klds[p ^ 1] + tid * 16) = rk0;
      *(f4*)(Klds[p ^ 1] + tid * 16 + 4096) = rk1;
      *(f4*)(Vlds[p ^ 1] + tid * 16) = rv0;
      *(f4*)(Vlds[p ^ 1] + tid * 16 + 4096) = rv1;
    }
  }
  lsumA += __shfl_xor(lsumA, 16);
  lsumA += __shfl_xor(lsumA, 32);
  lsumB += __shfl_xor(lsumB, 16);
  lsumB += __shfl_xor(lsumB, 32);
  const int rowgA = b * SLEN + qrowA;
  const int rowgB = b * SLEN + qrowB;
  const int NR = NB * SLEN;
  if (lane < 16) {
    Lp[z * NR + rowgA] = lsumA;
    Lp[z * NR + rowgB] = lsumB;
  }
  // bf16 partial store (cvt_pk): halves split traffic
  short* opA = Opb + ((size_t)z * NR + rowgA) * HP;
  short* opB = Opb + ((size_t)z * NR + rowgB) * HP;
#pragma unroll
  for (int n = 0; n < 4; ++n) {
    u2 ua, ub;
    asm("v_cvt_pk_bf16_f32 %0, %1, %2" : "=v"(ua[0]) : "v"(oA[n][0]), "v"(oA[n][1]));
    asm("v_cvt_pk_bf16_f32 %0, %1, %2" : "=v"(ua[1]) : "v"(oA[n][2]), "v"(oA[n][3]));
    asm("v_cvt_pk_bf16_f32 %0, %1, %2" : "=v"(ub[0]) : "v"(oB[n][0]), "v"(oB[n][1]));
    asm("v_cvt_pk_bf16_f32 %0, %1, %2" : "=v"(ub[1]) : "v"(oB[n][2]), "v"(oB[n][3]));
    *(u2*)(opA + 16 * n + 4 * g) = ua;
    *(u2*)(opB + 16 * n + 4 * g) = ub;
  }
}

// ------- fused: merge KV-split partials (plain sums) + out-projection --------
template <int NSPLIT>
__global__ __launch_bounds__(256) void combineproj_kernel(
    const float* __restrict__ Lp, const short* __restrict__ Opb,
    const short* __restrict__ wot, float* __restrict__ out) {
  const int lane = threadIdx.x & 63, wid = threadIdx.x >> 6;
  const int l15 = lane & 15, g = lane >> 4;
  const int sbase = blockIdx.x * 64 + wid * 16;
  const int row = sbase + l15;
  const int NR = NB * SLEN;
  float L = 0.f;
#pragma unroll
  for (int s = 0; s < NSPLIT; ++s) L += Lp[s * NR + row];
  float inv = 1.0f / L;
  s4 af[4];
#pragma unroll
  for (int c = 0; c < 4; ++c) {
    f4 acc = {};
#pragma unroll
    for (int s = 0; s < NSPLIT; ++s) {
      s4 sv = *(const s4*)(Opb + ((size_t)s * NR + row) * HP + 16 * c + 4 * g);
      acc[0] += bf2f(sv[0]);
      acc[1] += bf2f(sv[1]);
      acc[2] += bf2f(sv[2]);
      acc[3] += bf2f(sv[3]);
    }
#pragma unroll
    for (int r = 0; r < 4; ++r) af[c][r] = f2bf(acc[r] * inv);
  }
  for (int n = 0; n < 13; ++n) {
    f4 acc = {};
    const short* brow = wot + (16 * n + l15) * HP + 4 * g;
#pragma unroll
    for (int c = 0; c < 4; ++c) {
      s4 bf = *(const s4*)(brow + 16 * c);
      acc = __builtin_amdgcn_mfma_f32_16x16x16bf16_1k(af[c], bf, acc, 0, 0, 0);
    }
    int dm = 16 * n + l15;
    if (dm < DMODEL) {
#pragma unroll
      for (int r = 0; r < 4; ++r) {
        int rr = sbase + 4 * g + r;
        out[(size_t)rr * DMODEL + dm] = acc[r];
      }
    }
  }
}

extern "C" void kernel_launch(void* const* d_in, const int* in_sizes, int n_in,
                              void* d_out, int out_size, void* d_ws, size_t ws_size,
                              hipStream_t stream) {
  const float* q = (const float*)d_in[0];
  const float* k = (const float*)d_in[1];
  const float* v = (const float*)d_in[2];
  const float* WQ = (const float*)d_in[3];
  const float* WK = (const float*)d_in[4];
  const float* WV = (const float*)d_in[5];
  const float* WO = (const float*)d_in[6];
  float* out = (float*)d_out;
  char* ws = (char*)d_ws;

  const size_t MB2 = 2097152;  // 16384*64*2 bytes
  const size_t NR = (size_t)NB * SLEN;
  // KV-split 8 (bf16 partials); fall back to 4 if workspace is tight
  auto need = [&](int n) {
    return (size_t)131072 + 3 * MB2 + (size_t)n * NR * 4 + (size_t)n * NR * HP * 2;
  };
  int nsplit = (ws_size >= need(8)) ? 8 : 4;

  short* wot = (short*)(ws + 98304);
  short* Qp = (short*)(ws + 131072);
  short* Kp = (short*)(ws + 131072 + MB2);
  short* VpT = (short*)(ws + 131072 + 2 * MB2);
  float* Lp = (float*)(ws + 131072 + 3 * MB2);
  short* Opb = (short*)(Lp + nsplit * NR);

  proj_kernel<<<dim3(256, 1, 4), dim3(256), 0, stream>>>(q, k, v, WQ, WK, WV, WO,
                                                          Qp, Kp, VpT, wot);
  attn_kernel<<<dim3(32, NB, nsplit), dim3(256), 0, stream>>>(Qp, Kp, VpT, Lp, Opb);
  if (nsplit == 8)
    combineproj_kernel<8><<<dim3(256), dim3(256), 0, stream>>>(Lp, Opb, wot, out);
  else
    combineproj_kernel<4><<<dim3(256), dim3(256), 0, stream>>>(Lp, Opb, wot, out);
}